// Round 4
// baseline (101.896 us; speedup 1.0000x reference)
//
#include <hip/hip_runtime.h>
#include <hip/hip_fp16.h>

// Deformable 3D conv: B=2, CIN=COUT=64, D=8,H=32,W=32, K=27, stride=1,pad=1,dil=1
// Round 8 = round 7 with occupancy recut (grid was the occupancy cap: 768 blocks
// = exactly 3/CU):
//  - KGRP 3 -> 9: each block does ONE 3-k phase (no ph loop, 1 barrier). Grid
//    2304 blocks -> 4 blocks/CU resident (4 waves/SIMD, +33% latency hiding).
//  - LDS diet 49KB -> 38.9KB to allow 4 blocks/CU: LDW 72 -> 64 with T2 XOR
//    swizzle (byte ^= (row&7)<<4) on sW/sS; conflict-free (8 acc/bank min) and
//    16B-aligned. Coords packed 64B -> 32B/pos: {base,wD,hD,dD} int4 + 8 half
//    weights; corner offsets rebuilt with same 8 adds; weight broadcast folds
//    into v_pk_fma_f16 op_sel. 4 -> 2 ds_read_b128 per sampling iter.
//  - __launch_bounds__(256,4). Extra cost: 3x out atomic traffic (~+0.3us).

#define BB    2
#define CINC  64
#define COUTC 64
#define DDEP  8
#define HGT   32
#define WID   32
#define KK    27
#define KGRP  9
#define KPB   3         // k's per block
#define PP    8192      // DOUT*HOUT*WOUT
#define TP    64        // output positions per workgroup

typedef _Float16 f16x8 __attribute__((ext_vector_type(8)));
typedef float f32x4 __attribute__((ext_vector_type(4)));
typedef unsigned int u32x4 __attribute__((ext_vector_type(4)));

__device__ __forceinline__ __half2 h2(unsigned v) { return __builtin_bit_cast(__half2, v); }
__device__ __forceinline__ unsigned h2u(__half2 h) { return __builtin_bit_cast(unsigned, h); }
__device__ __forceinline__ __half2 blo(unsigned v) { return __half2half2(__low2half(h2(v))); }
__device__ __forceinline__ __half2 bhi(unsigned v) { return __half2half2(__high2half(h2(v))); }

// accumulate one corner: 16B (8 channels as 4 half2) * broadcast half2 weight
__device__ __forceinline__ void acc8h(const char* __restrict__ xc, int off, __half2 uu,
                                      __half2& s0, __half2& s1, __half2& s2, __half2& s3) {
    u32x4 v = *(const u32x4*)(xc + off);
    s0 = __hfma2(h2(v.x), uu, s0);
    s1 = __hfma2(h2(v.y), uu, s1);
    s2 = __hfma2(h2(v.z), uu, s2);
    s3 = __hfma2(h2(v.w), uu, s3);
}

// Fused pre-kernel:
//  blocks [0,256): transpose+convert x[b][c][s] fp32 -> xt[b][s][c] fp16
//  blocks [256,688): weight (COUT,CIN,27) fp32 -> wt[(k*64+o)*64+c] fp16
//  blocks [688,1712): zero-init out (replaces hipMemsetAsync dispatch)
#define WBLOCKS 432   // KK*COUTC*CINC / 256
#define ZBLOCKS 1024  // BB*COUTC*PP / 4 / 256
__global__ void pre_kernel(const float* __restrict__ x, const float* __restrict__ w,
                           unsigned short* __restrict__ xt, unsigned short* __restrict__ wt,
                           float* __restrict__ out) {
    __shared__ float sT[64][65];
    const int t    = threadIdx.x;
    const int lane = t & 63;
    const int wv   = t >> 6;
    const int half = lane >> 5;
    const int c2   = lane & 31;
    int blk = blockIdx.x;
    if (blk < 256) {
        int b  = blk >> 7;
        int s0 = (blk & 127) * 64;
        #pragma unroll
        for (int i = 0; i < 16; ++i) {
            int c = wv * 16 + i;
            sT[c][lane] = x[(size_t)(b * CINC + c) * PP + s0 + lane];
        }
        __syncthreads();
        #pragma unroll
        for (int i = 0; i < 8; ++i) {
            int s = wv * 16 + 2 * i + half;
            unsigned pk = h2u(__floats2half2_rn(sT[2 * c2][s], sT[2 * c2 + 1][s]));
            *(unsigned*)&xt[(size_t)(b * PP + s0 + s) * 64 + 2 * c2] = pk;
        }
    } else if (blk < 256 + WBLOCKS) {
        int id = (blk - 256) * 256 + t;
        if (id < KK * COUTC * CINC) {
            int c = id & 63;
            int o = (id >> 6) & 63;
            int k = id >> 12;
            __half hw = __float2half(w[(o * CINC + c) * KK + k]);
            wt[id] = __builtin_bit_cast(unsigned short, hw);
        }
    } else {
        int id = (blk - 256 - WBLOCKS) * 256 + t;   // float4 index
        ((float4*)out)[id] = make_float4(0.f, 0.f, 0.f, 0.f);
    }
}

__global__ __launch_bounds__(256, 4) void deform_kernel(
    const unsigned short* __restrict__ xt, const float* __restrict__ off,
    const unsigned short* __restrict__ wt, const float* __restrict__ bias,
    float* __restrict__ out)
{
    // XOR-swizzled tiles: elem (row, col) lives at byte row*128 + ((2*col) ^ ((row&7)<<4))
    __shared__ unsigned short sW[KPB * COUTC * 64] __attribute__((aligned(16))); // 24576 B
    __shared__ unsigned short sS[TP * 64]          __attribute__((aligned(16))); // 8192 B
    __shared__ int sCrd[KPB][TP][8] __attribute__((aligned(16)));                // 6144 B
    // sCrd[..][0..3] = {base, wDelta, hDelta, dDelta}; [4..7] = 8 half weights (pairs)

    const int t     = threadIdx.x;
    const int lane  = t & 63;
    const int wv    = t >> 6;
    const int choct = lane & 7;          // channel octet (8 channels)
    const int g8    = lane >> 3;         // position within iteration (0..7)
    const int ch16  = 16 * choct;        // byte offset of channel octet
    const int b     = blockIdx.x >> 7;
    const int p0    = (blockIdx.x & 127) * TP;
    const int kg    = blockIdx.y;
    const int kbase = kg * KPB;

    const char* __restrict__ xc = (const char*)xt + (size_t)b * PP * 128;
    char* sWb = (char*)sW;
    char* sSb = (char*)sS;

    f32x4 acc[4];
    #pragma unroll
    for (int g = 0; g < 4; ++g) acc[g] = (f32x4)0.0f;

    const int n0  = lane & 15;
    const int q   = lane >> 4;
    const int cr  = lane & 15;   // coord row within wave slice
    const int ckl = lane >> 4;   // coord kl (0..3, 3 idle)

    // ---- stage 3 weight tiles into swizzled sW (coalesced 16B loads)
    {
        const unsigned short* wk = wt + kbase * (COUTC * CINC);
        #pragma unroll
        for (int j = 0; j < 6; ++j) {
            int idx = j * 2048 + t * 8;              // elem index in wt [kl][o][c]
            int kl  = idx >> 12;
            int o   = (idx >> 6) & 63;
            int cb  = (idx & 63) * 2;                // col byte (16B aligned)
            *(f16x8*)(sWb + kl * 8192 + o * 128 + (cb ^ ((o & 7) << 4))) =
                *(const f16x8*)(wk + idx);
        }
    }

    // ---- coords: each wave computes its OWN 16 rows x 3 kl (48 lanes)
    if (ckl < KPB) {
        int k  = kbase + ckl;
        int pl = 16 * wv + cr;
        int pp = p0 + pl;
        int ow = pp & 31;
        int oh = (pp >> 5) & 31;
        int od = pp >> 10;
        int kd = k / 9;
        int kh = (k - kd * 9) / 3;
        int kw = k - kd * 9 - kh * 3;
        const float* ob = off + (size_t)(b * (3 * KK) + 3 * k) * PP + pp;
        float zd = (float)(od - 1 + kd) + ob[0];
        float zh = (float)(oh - 1 + kh) + ob[PP];
        float zw = (float)(ow - 1 + kw) + ob[2 * PP];

        float fdf = floorf(zd); int d0 = (int)fdf; float fd = zd - fdf;
        float fhf = floorf(zh); int h0 = (int)fhf; float fh = zh - fhf;
        float fwf = floorf(zw); int w0 = (int)fwf; float fw = zw - fwf;

        float Bd0 = (d0 >= 0     && d0 < DDEP)     ? 1.0f - fd : 0.0f;
        float Bd1 = (d0 + 1 >= 0 && d0 + 1 < DDEP) ? fd        : 0.0f;
        float Ch0 = (h0 >= 0     && h0 < HGT)      ? 1.0f - fh : 0.0f;
        float Ch1 = (h0 + 1 >= 0 && h0 + 1 < HGT)  ? fh        : 0.0f;
        float Aw0 = (w0 >= 0     && w0 < WID)      ? 1.0f - fw : 0.0f;
        float Aw1 = (w0 + 1 >= 0 && w0 + 1 < WID)  ? fw        : 0.0f;
        int dc0 = min(max(d0, 0), DDEP - 1);
        int dc1 = min(max(d0 + 1, 0), DDEP - 1);
        int hc0 = min(max(h0, 0), HGT - 1);
        int hc1 = min(max(h0 + 1, 0), HGT - 1);
        int wc0 = min(max(w0, 0), WID - 1);
        int wc1 = min(max(w0 + 1, 0), WID - 1);

        // BYTE offsets: one (d,h,w) line = 64 ch * 2B = 128B
        int base = (dc0 * HGT + hc0) * (WID * 128) + wc0 * 128;
        int wD   = (wc1 - wc0) * 128;
        int hD   = (hc1 - hc0) * (WID * 128);
        int dD   = (dc1 - dc0) * (HGT * WID * 128);
        sCrd[ckl][pl][0] = base;
        sCrd[ckl][pl][1] = wD;
        sCrd[ckl][pl][2] = hD;
        sCrd[ckl][pl][3] = dD;
        float bc0 = Bd0 * Ch0, bc1 = Bd0 * Ch1, bc2 = Bd1 * Ch0, bc3 = Bd1 * Ch1;
        sCrd[ckl][pl][4] = (int)h2u(__floats2half2_rn(bc0 * Aw0, bc0 * Aw1)); // u0,u1
        sCrd[ckl][pl][5] = (int)h2u(__floats2half2_rn(bc1 * Aw0, bc1 * Aw1)); // u2,u3
        sCrd[ckl][pl][6] = (int)h2u(__floats2half2_rn(bc2 * Aw0, bc2 * Aw1)); // u4,u5
        sCrd[ckl][pl][7] = (int)h2u(__floats2half2_rn(bc3 * Aw0, bc3 * Aw1)); // u6,u7
    }
    __syncthreads();   // sW + coords visible

    // ---- barrier-free kl loop: sample own 16 rows -> private swizzled sS -> MFMA
    const int sw   = (n0 & 7) << 4;   // row-dependent XOR for MFMA reads
    const int cb0  = (16 * q) ^ sw;
    const int cb1  = (64 + 16 * q) ^ sw;
    #pragma unroll
    for (int kl = 0; kl < KPB; ++kl) {
        #pragma unroll
        for (int it = 0; it < 2; ++it) {
            int prow = 16 * wv + 8 * it + g8;
            const int4  ib = *(const int4*)&sCrd[kl][prow][0];
            const u32x4 cw = *(const u32x4*)&sCrd[kl][prow][4];
            int o0 = ib.x + ch16;
            int o1 = o0 + ib.y;
            int o2 = o0 + ib.z;
            int o3 = o2 + ib.y;
            int o4 = o0 + ib.w;
            int o5 = o4 + ib.y;
            int o6 = o4 + ib.z;
            int o7 = o6 + ib.y;
            __half2 s0 = h2(0u), s1 = h2(0u), s2 = h2(0u), s3 = h2(0u);
            acc8h(xc, o0, blo(cw.x), s0, s1, s2, s3);
            acc8h(xc, o1, bhi(cw.x), s0, s1, s2, s3);
            acc8h(xc, o2, blo(cw.y), s0, s1, s2, s3);
            acc8h(xc, o3, bhi(cw.y), s0, s1, s2, s3);
            acc8h(xc, o4, blo(cw.z), s0, s1, s2, s3);
            acc8h(xc, o5, bhi(cw.z), s0, s1, s2, s3);
            acc8h(xc, o6, blo(cw.w), s0, s1, s2, s3);
            acc8h(xc, o7, bhi(cw.w), s0, s1, s2, s3);
            u32x4 pk = {h2u(s0), h2u(s1), h2u(s2), h2u(s3)};
            *(u32x4*)(sSb + prow * 128 + (ch16 ^ ((prow & 7) << 4))) = pk;
        }

        // ---- MFMA: wave's 16 positions x all 64 COUT, Kdim=64
        {
            const char* sWk = sWb + kl * 8192;
            const int rowB = (16 * wv + n0) * 128;
            f16x8 b0 = *(const f16x8*)(sSb + rowB + cb0);
            f16x8 b1 = *(const f16x8*)(sSb + rowB + cb1);
            __builtin_amdgcn_s_setprio(1);
            #pragma unroll
            for (int g = 0; g < 4; ++g) {
                f16x8 a0 = *(const f16x8*)(sWk + (16 * g + n0) * 128 + cb0);
                f16x8 a1 = *(const f16x8*)(sWk + (16 * g + n0) * 128 + cb1);
                acc[g] = __builtin_amdgcn_mfma_f32_16x16x32_f16(a0, b0, acc[g], 0, 0, 0);
                acc[g] = __builtin_amdgcn_mfma_f32_16x16x32_f16(a1, b1, acc[g], 0, 0, 0);
            }
            __builtin_amdgcn_s_setprio(0);
        }
    }

    // ---- epilogue: atomic partial accumulate; bias added by kg==0.
    const int p = p0 + 16 * wv + n0;
    #pragma unroll
    for (int g = 0; g < 4; ++g) {
        #pragma unroll
        for (int r = 0; r < 4; ++r) {
            int o = 16 * g + 4 * q + r;
            float v = acc[g][r];
            if (kg == 0) v += bias[o];
            unsafeAtomicAdd(&out[(size_t)(b * COUTC + o) * PP + p], v);
        }
    }
}

extern "C" void kernel_launch(void* const* d_in, const int* in_sizes, int n_in,
                              void* d_out, int out_size, void* d_ws, size_t ws_size,
                              hipStream_t stream) {
    const float* x    = (const float*)d_in[0];
    const float* off  = (const float*)d_in[1];
    const float* w    = (const float*)d_in[2];
    const float* bias = (const float*)d_in[3];
    float* out        = (float*)d_out;

    unsigned short* xt = (unsigned short*)d_ws;                       // 2*8192*64*2 = 2 MB
    unsigned short* wt = (unsigned short*)((char*)d_ws + (size_t)BB * PP * 64 * 2); // 221184 B

    hipLaunchKernelGGL(pre_kernel, dim3(256 + WBLOCKS + ZBLOCKS), dim3(256), 0,
                       stream, x, w, xt, wt, out);
    hipLaunchKernelGGL(deform_kernel, dim3(BB * (PP / TP), KGRP), dim3(256), 0, stream,
                       xt, off, wt, bias, out);
}

// Round 5
// 91.752 us; speedup vs baseline: 1.1106x; 1.1106x over previous
//
#include <hip/hip_runtime.h>
#include <hip/hip_fp16.h>

// Deformable 3D conv: B=2, CIN=COUT=64, D=8,H=32,W=32, K=27, stride=1,pad=1,dil=1
// Round 9 = REVERT to round 7 (92.25us: KGRP=3, 3-phase, LDW=72 pad, lb(256,3),
// fp16 packed math) + keep ONLY round 8's compressed coords:
//  - sCrd 32B/pos: {base,wD,hD,dD} int4 + 4x u32 packed half2 corner weights
//    -> 2 ds_read_b128 per sampling iter (was 4), coord LDS 12.3K -> 6K.
//  - Round 8's KGRP=9 regression traced to 3x atomic RMW traffic + 3x per-block
//    fixed overhead + lb(256,4) register squeeze; all reverted here.

#define BB    2
#define CINC  64
#define COUTC 64
#define DDEP  8
#define HGT   32
#define WID   32
#define KK    27
#define KGRP  3
#define KPG   9         // k's per blockIdx.y group
#define KPH   3         // k's per phase (weight-stage batch)
#define PP    8192      // DOUT*HOUT*WOUT
#define TP    64        // output positions per workgroup
#define LDW   72        // padded LDS row stride (fp16 elems)

typedef _Float16 f16x8 __attribute__((ext_vector_type(8)));
typedef float f32x4 __attribute__((ext_vector_type(4)));
typedef unsigned int u32x4 __attribute__((ext_vector_type(4)));

__device__ __forceinline__ __half2 h2(unsigned v) { return __builtin_bit_cast(__half2, v); }
__device__ __forceinline__ unsigned h2u(__half2 h) { return __builtin_bit_cast(unsigned, h); }
__device__ __forceinline__ __half2 blo(unsigned v) { return __half2half2(__low2half(h2(v))); }
__device__ __forceinline__ __half2 bhi(unsigned v) { return __half2half2(__high2half(h2(v))); }

// accumulate one corner: 16B (8 channels as 4 half2) * broadcast half2 weight
__device__ __forceinline__ void acc8h(const char* __restrict__ xc, int off, __half2 uu,
                                      __half2& s0, __half2& s1, __half2& s2, __half2& s3) {
    u32x4 v = *(const u32x4*)(xc + off);
    s0 = __hfma2(h2(v.x), uu, s0);
    s1 = __hfma2(h2(v.y), uu, s1);
    s2 = __hfma2(h2(v.z), uu, s2);
    s3 = __hfma2(h2(v.w), uu, s3);
}

// Fused pre-kernel:
//  blocks [0,256): transpose+convert x[b][c][s] fp32 -> xt[b][s][c] fp16
//  blocks [256,688): weight (COUT,CIN,27) fp32 -> wt[(k*64+o)*64+c] fp16
//  blocks [688,1712): zero-init out (replaces hipMemsetAsync dispatch)
#define WBLOCKS 432   // KK*COUTC*CINC / 256
#define ZBLOCKS 1024  // BB*COUTC*PP / 4 / 256
__global__ void pre_kernel(const float* __restrict__ x, const float* __restrict__ w,
                           unsigned short* __restrict__ xt, unsigned short* __restrict__ wt,
                           float* __restrict__ out) {
    __shared__ float sT[64][65];
    const int t    = threadIdx.x;
    const int lane = t & 63;
    const int wv   = t >> 6;
    const int half = lane >> 5;
    const int c2   = lane & 31;
    int blk = blockIdx.x;
    if (blk < 256) {
        int b  = blk >> 7;
        int s0 = (blk & 127) * 64;
        #pragma unroll
        for (int i = 0; i < 16; ++i) {
            int c = wv * 16 + i;
            sT[c][lane] = x[(size_t)(b * CINC + c) * PP + s0 + lane];
        }
        __syncthreads();
        #pragma unroll
        for (int i = 0; i < 8; ++i) {
            int s = wv * 16 + 2 * i + half;
            unsigned pk = h2u(__floats2half2_rn(sT[2 * c2][s], sT[2 * c2 + 1][s]));
            *(unsigned*)&xt[(size_t)(b * PP + s0 + s) * 64 + 2 * c2] = pk;
        }
    } else if (blk < 256 + WBLOCKS) {
        int id = (blk - 256) * 256 + t;
        if (id < KK * COUTC * CINC) {
            int c = id & 63;
            int o = (id >> 6) & 63;
            int k = id >> 12;
            __half hw = __float2half(w[(o * CINC + c) * KK + k]);
            wt[id] = __builtin_bit_cast(unsigned short, hw);
        }
    } else {
        int id = (blk - 256 - WBLOCKS) * 256 + t;   // float4 index
        ((float4*)out)[id] = make_float4(0.f, 0.f, 0.f, 0.f);
    }
}

__global__ __launch_bounds__(256, 3) void deform_kernel(
    const unsigned short* __restrict__ xt, const float* __restrict__ off,
    const unsigned short* __restrict__ wt, const float* __restrict__ bias,
    float* __restrict__ out)
{
    __shared__ unsigned short sW[KPH * COUTC * LDW] __attribute__((aligned(16))); // 3x [o][c]
    __shared__ unsigned short sS[TP * LDW]          __attribute__((aligned(16))); // [p][c] wave-private slices
    __shared__ int sCrd[KPH][TP][8] __attribute__((aligned(16)));                 // 6144 B
    // sCrd[..][0..3] = {base, wDelta, hDelta, dDelta}; [4..7] = 8 half weights (pairs)

    const int t     = threadIdx.x;
    const int lane  = t & 63;
    const int wv    = t >> 6;
    const int choct = lane & 7;          // channel octet (8 channels)
    const int g8    = lane >> 3;         // position within iteration (0..7)
    const int ch16  = 16 * choct;        // byte offset of channel octet
    const int b     = blockIdx.x >> 7;
    const int p0    = (blockIdx.x & 127) * TP;
    const int kg    = blockIdx.y;

    const char* __restrict__ xc = (const char*)xt + (size_t)b * PP * 128;

    f32x4 acc[4];
    #pragma unroll
    for (int g = 0; g < 4; ++g) acc[g] = (f32x4)0.0f;

    const int n0  = lane & 15;
    const int q   = lane >> 4;
    const int cr  = lane & 15;   // coord row within wave slice
    const int ckl = lane >> 4;   // coord kl (0..3, 3 idle)

    #pragma unroll 1
    for (int ph = 0; ph < 3; ++ph) {
        const int kbase = kg * KPG + ph * KPH;

        __syncthreads();   // all waves done reading sW/sCrd of previous phase

        // ---- stage 3 weight tiles (coalesced 16B loads)
        const unsigned short* wk = wt + kbase * (COUTC * CINC);
        #pragma unroll
        for (int j = 0; j < 6; ++j) {
            int idx = j * 2048 + t * 8;
            int kl  = idx >> 12;
            int rem = idx & 4095;
            *(f16x8*)&sW[kl * (COUTC * LDW) + (rem >> 6) * LDW + (rem & 63)] =
                *(const f16x8*)(wk + idx);
        }

        // ---- coords: each wave computes its OWN 16 rows x 3 kl (48 lanes)
        if (ckl < KPH) {
            int k  = kbase + ckl;
            int pl = 16 * wv + cr;
            int pp = p0 + pl;
            int ow = pp & 31;
            int oh = (pp >> 5) & 31;
            int od = pp >> 10;
            int kd = k / 9;
            int kh = (k - kd * 9) / 3;
            int kw = k - kd * 9 - kh * 3;
            const float* ob = off + (size_t)(b * (3 * KK) + 3 * k) * PP + pp;
            float zd = (float)(od - 1 + kd) + ob[0];
            float zh = (float)(oh - 1 + kh) + ob[PP];
            float zw = (float)(ow - 1 + kw) + ob[2 * PP];

            float fdf = floorf(zd); int d0 = (int)fdf; float fd = zd - fdf;
            float fhf = floorf(zh); int h0 = (int)fhf; float fh = zh - fhf;
            float fwf = floorf(zw); int w0 = (int)fwf; float fw = zw - fwf;

            float Bd0 = (d0 >= 0     && d0 < DDEP)     ? 1.0f - fd : 0.0f;
            float Bd1 = (d0 + 1 >= 0 && d0 + 1 < DDEP) ? fd        : 0.0f;
            float Ch0 = (h0 >= 0     && h0 < HGT)      ? 1.0f - fh : 0.0f;
            float Ch1 = (h0 + 1 >= 0 && h0 + 1 < HGT)  ? fh        : 0.0f;
            float Aw0 = (w0 >= 0     && w0 < WID)      ? 1.0f - fw : 0.0f;
            float Aw1 = (w0 + 1 >= 0 && w0 + 1 < WID)  ? fw        : 0.0f;
            int dc0 = min(max(d0, 0), DDEP - 1);
            int dc1 = min(max(d0 + 1, 0), DDEP - 1);
            int hc0 = min(max(h0, 0), HGT - 1);
            int hc1 = min(max(h0 + 1, 0), HGT - 1);
            int wc0 = min(max(w0, 0), WID - 1);
            int wc1 = min(max(w0 + 1, 0), WID - 1);

            // BYTE offsets: one (d,h,w) line = 64 ch * 2B = 128B
            int base = (dc0 * HGT + hc0) * (WID * 128) + wc0 * 128;
            int wD   = (wc1 - wc0) * 128;
            int hD   = (hc1 - hc0) * (WID * 128);
            int dD   = (dc1 - dc0) * (HGT * WID * 128);
            sCrd[ckl][pl][0] = base;
            sCrd[ckl][pl][1] = wD;
            sCrd[ckl][pl][2] = hD;
            sCrd[ckl][pl][3] = dD;
            float bc0 = Bd0 * Ch0, bc1 = Bd0 * Ch1, bc2 = Bd1 * Ch0, bc3 = Bd1 * Ch1;
            sCrd[ckl][pl][4] = (int)h2u(__floats2half2_rn(bc0 * Aw0, bc0 * Aw1));
            sCrd[ckl][pl][5] = (int)h2u(__floats2half2_rn(bc1 * Aw0, bc1 * Aw1));
            sCrd[ckl][pl][6] = (int)h2u(__floats2half2_rn(bc2 * Aw0, bc2 * Aw1));
            sCrd[ckl][pl][7] = (int)h2u(__floats2half2_rn(bc3 * Aw0, bc3 * Aw1));
        }
        __syncthreads();   // sW (and coords) visible

        // ---- barrier-free kl loop: sample own 16 rows -> private sS slice -> MFMA
        #pragma unroll
        for (int kl = 0; kl < KPH; ++kl) {
            #pragma unroll
            for (int it = 0; it < 2; ++it) {
                int prow = 16 * wv + 8 * it + g8;
                const int4  ib = *(const int4*)&sCrd[kl][prow][0];
                const u32x4 cw = *(const u32x4*)&sCrd[kl][prow][4];
                int o0 = ib.x + ch16;       // (d0,h0,w0)
                int o1 = o0 + ib.y;         // (d0,h0,w1)
                int o2 = o0 + ib.z;         // (d0,h1,w0)
                int o3 = o2 + ib.y;         // (d0,h1,w1)
                int o4 = o0 + ib.w;         // (d1,h0,w0)
                int o5 = o4 + ib.y;         // (d1,h0,w1)
                int o6 = o4 + ib.z;         // (d1,h1,w0)
                int o7 = o6 + ib.y;         // (d1,h1,w1)
                __half2 s0 = h2(0u), s1 = h2(0u), s2 = h2(0u), s3 = h2(0u);
                acc8h(xc, o0, blo(cw.x), s0, s1, s2, s3);
                acc8h(xc, o1, bhi(cw.x), s0, s1, s2, s3);
                acc8h(xc, o2, blo(cw.y), s0, s1, s2, s3);
                acc8h(xc, o3, bhi(cw.y), s0, s1, s2, s3);
                acc8h(xc, o4, blo(cw.z), s0, s1, s2, s3);
                acc8h(xc, o5, bhi(cw.z), s0, s1, s2, s3);
                acc8h(xc, o6, blo(cw.w), s0, s1, s2, s3);
                acc8h(xc, o7, bhi(cw.w), s0, s1, s2, s3);
                u32x4 pk = {h2u(s0), h2u(s1), h2u(s2), h2u(s3)};
                *(u32x4*)&sS[prow * LDW + 8 * choct] = pk;
            }

            // ---- MFMA: wave's 16 positions x all 64 COUT, Kdim=64
            {
                const unsigned short* sWk = &sW[kl * (COUTC * LDW)];
                f16x8 b0 = *(const f16x8*)&sS[(16 * wv + n0) * LDW +      8 * q];
                f16x8 b1 = *(const f16x8*)&sS[(16 * wv + n0) * LDW + 32 + 8 * q];
                __builtin_amdgcn_s_setprio(1);
                #pragma unroll
                for (int g = 0; g < 4; ++g) {
                    f16x8 a0 = *(const f16x8*)&sWk[(16 * g + n0) * LDW +      8 * q];
                    f16x8 a1 = *(const f16x8*)&sWk[(16 * g + n0) * LDW + 32 + 8 * q];
                    acc[g] = __builtin_amdgcn_mfma_f32_16x16x32_f16(a0, b0, acc[g], 0, 0, 0);
                    acc[g] = __builtin_amdgcn_mfma_f32_16x16x32_f16(a1, b1, acc[g], 0, 0, 0);
                }
                __builtin_amdgcn_s_setprio(0);
            }
        }
    }

    // ---- epilogue: atomic partial accumulate; bias added by kg==0.
    const int p = p0 + 16 * wv + n0;
    #pragma unroll
    for (int g = 0; g < 4; ++g) {
        #pragma unroll
        for (int r = 0; r < 4; ++r) {
            int o = 16 * g + 4 * q + r;
            float v = acc[g][r];
            if (kg == 0) v += bias[o];
            unsafeAtomicAdd(&out[(size_t)(b * COUTC + o) * PP + p], v);
        }
    }
}

extern "C" void kernel_launch(void* const* d_in, const int* in_sizes, int n_in,
                              void* d_out, int out_size, void* d_ws, size_t ws_size,
                              hipStream_t stream) {
    const float* x    = (const float*)d_in[0];
    const float* off  = (const float*)d_in[1];
    const float* w    = (const float*)d_in[2];
    const float* bias = (const float*)d_in[3];
    float* out        = (float*)d_out;

    unsigned short* xt = (unsigned short*)d_ws;                       // 2*8192*64*2 = 2 MB
    unsigned short* wt = (unsigned short*)((char*)d_ws + (size_t)BB * PP * 64 * 2); // 221184 B

    hipLaunchKernelGGL(pre_kernel, dim3(256 + WBLOCKS + ZBLOCKS), dim3(256), 0,
                       stream, x, w, xt, wt, out);
    hipLaunchKernelGGL(deform_kernel, dim3(BB * (PP / TP), KGRP), dim3(256), 0, stream,
                       xt, off, wt, bias, out);
}